// Round 4
// baseline (440.340 us; speedup 1.0000x reference)
//
#include <hip/hip_runtime.h>
#include <hip/hip_cooperative_groups.h>

namespace cg = cooperative_groups;

// Problem constants
#define N_ROWS (16 * 8192)   // 131072 rows of 208 channels
#define NCH 208
#define CH_JMP 90            // OPCODE_START(88) + OP_JMP(2)
#define CH_BZ  92            // 88 + 4
#define CH_BNZ 93            // 88 + 5

// Clang native vector type: required by __builtin_nontemporal_store.
typedef float vf4 __attribute__((ext_vector_type(4)));

// Flag slots hold this magic iff set. d_ws is poisoned to 0xAAAAAAAA (!= MAGIC)
// before every call, so no memset is needed; races are idempotent stores.
#define FLAG_MAGIC 0x7F1A6501

// ---------------------------------------------------------------------------
// Fused cooperative kernel. 512 blocks x 256 threads (2 blocks/CU -> all
// co-resident, grid.sync() is safe).
//   Phase 1: 1 thread/row checks the 3 opcode channels; wave-__any + one
//            idempotent agent-scope store per wave per flag.
//   grid.sync(): device-scope acq-rel barrier publishes flags across XCDs.
//   Phase 2: 64 rows/wave. Lanes 0..51 move one float4 (52*16B = 832B = one
//            row, contiguous). Row scalars (imm/pc/ax, channels 163..202) are
//            extracted from the in-register row via __shfl (lanes 40..50)
//            instead of re-loading — 2 VMEM insts/row instead of 26.
//            2-deep pipeline: row r+1's load is issued before row r's patch.
// Chunk->channel map (chunk c = channels [4c, 4c+3]):
//   42.w = ch171 (nib0), 43.xyzw = ch172..175 (nibs1..4),
//   44.xyz = ch176..178 (nibs5..7), 50.w = ch203 (branch_taken)
// ---------------------------------------------------------------------------
__global__ __launch_bounds__(256) void cfe_fused_k(const float* __restrict__ x,
                                                   float* __restrict__ out,
                                                   int* __restrict__ flags) {
    const int tid  = blockIdx.x * 256 + threadIdx.x;   // == row for phase 1
    const int lane = threadIdx.x & 63;

    // ---- Phase 1: global any() over opcode channels ----
    {
        const float* rp = x + (size_t)tid * NCH;
        bool j  = rp[CH_JMP] > 0.5f;
        bool z  = rp[CH_BZ]  > 0.5f;
        bool nz = rp[CH_BNZ] > 0.5f;
        if (__any(j)  && lane == 0)
            __hip_atomic_store(flags + 0, FLAG_MAGIC, __ATOMIC_RELAXED, __HIP_MEMORY_SCOPE_AGENT);
        if (__any(z)  && lane == 0)
            __hip_atomic_store(flags + 1, FLAG_MAGIC, __ATOMIC_RELAXED, __HIP_MEMORY_SCOPE_AGENT);
        if (__any(nz) && lane == 0)
            __hip_atomic_store(flags + 2, FLAG_MAGIC, __ATOMIC_RELAXED, __HIP_MEMORY_SCOPE_AGENT);
    }

    cg::this_grid().sync();

    // ---- Phase 2: copy + patch, 64 rows per wave ----
    const bool fj  = __hip_atomic_load(flags + 0, __ATOMIC_RELAXED, __HIP_MEMORY_SCOPE_AGENT) == FLAG_MAGIC;
    const bool fz  = __hip_atomic_load(flags + 1, __ATOMIC_RELAXED, __HIP_MEMORY_SCOPE_AGENT) == FLAG_MAGIC;
    const bool fnz = __hip_atomic_load(flags + 2, __ATOMIC_RELAXED, __HIP_MEMORY_SCOPE_AGENT) == FLAG_MAGIC;
    const bool anyf = fj | fz | fnz;

    const int gwave = tid >> 6;                        // 0..2047
    const vf4* src = (const vf4*)(x   + (size_t)gwave * 64 * NCH);
    vf4*       dst = (vf4*)      (out + (size_t)gwave * 64 * NCH);

    vf4 v = {0.f, 0.f, 0.f, 0.f};
    if (lane < 52) v = src[lane];

#pragma unroll 4
    for (int r = 0; r < 64; ++r) {
        // issue next row's load before touching this row (2-deep pipeline)
        vf4 vn = {0.f, 0.f, 0.f, 0.f};
        if (r < 63 && lane < 52) vn = src[(r + 1) * 52 + lane];

        if (anyf) {
            // Extract channels 163..202 from the wave's registers via shuffle.
            // ch -> (lane ch>>2, comp ch&3). All 64 lanes execute (uniform
            // branch), sources are lanes 40..50 which hold valid data.
            float imm = 0.0f, pc = 0.0f;
            int   ax  = 0;
            float p   = 1.0f;   // 16^i: exact powers of two -> products exact;
            int   pi  = 1;      // only the sequential i=0..7 add order rounds.

            // i=0: ax ch163=(40,w)  pc ch171=(42,w)  imm ch195=(48,w)
            ax  += ((int)__shfl(v.w, 40)) * pi;
            pc  += __shfl(v.w, 42) * p;
            imm += __shfl(v.w, 48) * p;  pi <<= 4; p *= 16.0f;
            // i=1..4: ax ch164..167=(41,xyzw)  pc ch172..175=(43,xyzw)  imm ch196..199=(49,xyzw)
            ax  += ((int)__shfl(v.x, 41)) * pi;
            pc  += __shfl(v.x, 43) * p;
            imm += __shfl(v.x, 49) * p;  pi <<= 4; p *= 16.0f;
            ax  += ((int)__shfl(v.y, 41)) * pi;
            pc  += __shfl(v.y, 43) * p;
            imm += __shfl(v.y, 49) * p;  pi <<= 4; p *= 16.0f;
            ax  += ((int)__shfl(v.z, 41)) * pi;
            pc  += __shfl(v.z, 43) * p;
            imm += __shfl(v.z, 49) * p;  pi <<= 4; p *= 16.0f;
            ax  += ((int)__shfl(v.w, 41)) * pi;
            pc  += __shfl(v.w, 43) * p;
            imm += __shfl(v.w, 49) * p;  pi <<= 4; p *= 16.0f;
            // i=5..7: ax ch168..170=(42,xyz)  pc ch176..178=(44,xyz)  imm ch200..202=(50,xyz)
            ax  += ((int)__shfl(v.x, 42)) * pi;
            pc  += __shfl(v.x, 44) * p;
            imm += __shfl(v.x, 50) * p;  pi <<= 4; p *= 16.0f;
            ax  += ((int)__shfl(v.y, 42)) * pi;
            pc  += __shfl(v.y, 44) * p;
            imm += __shfl(v.y, 50) * p;  pi <<= 4; p *= 16.0f;
            ax  += ((int)__shfl(v.z, 42)) * pi;
            pc  += __shfl(v.z, 44) * p;
            imm += __shfl(v.z, 50) * p;

            bool az = (ax == 0);
            float new_pc, bt;
            if (fj)      { new_pc = imm;                  bt = 1.0f; }
            else if (fz) { new_pc = az ? imm : pc + 8.0f; bt = az ? 1.0f : 0.0f; }
            else         { new_pc = az ? pc + 8.0f : imm; bt = az ? 0.0f : 1.0f; }

            int ip = (int)new_pc;  // trunc toward zero; >> arithmetic == numpy
            if (lane == 42) {
                v.w = (float)(ip & 15);
            } else if (lane == 43) {
                v.x = (float)((ip >>  4) & 15);
                v.y = (float)((ip >>  8) & 15);
                v.z = (float)((ip >> 12) & 15);
                v.w = (float)((ip >> 16) & 15);
            } else if (lane == 44) {
                v.x = (float)((ip >> 20) & 15);
                v.y = (float)((ip >> 24) & 15);
                v.z = (float)((ip >> 28) & 15);
            } else if (lane == 50) {
                v.w = bt;
            }
        }

        if (lane < 52) {
            // Output never re-read -> NT store keeps L2 for the input stream.
            __builtin_nontemporal_store(v, &dst[r * 52 + lane]);
        }
        v = vn;
    }
}

extern "C" void kernel_launch(void* const* d_in, const int* in_sizes, int n_in,
                              void* d_out, int out_size, void* d_ws, size_t ws_size,
                              hipStream_t stream) {
    const float* x = (const float*)d_in[0];
    float* out     = (float*)d_out;
    int* flags     = (int*)d_ws;

    void* args[] = { (void*)&x, (void*)&out, (void*)&flags };
    hipLaunchCooperativeKernel((const void*)cfe_fused_k,
                               dim3(512), dim3(256), args, 0, stream);
}